// Round 5
// baseline (75.301 us; speedup 1.0000x reference)
//
#include <hip/hip_runtime.h>
#include <math.h>

#define B_DIM    1024
#define IN_DIMS  512
#define OUT_DIMS 512
#define MOD_DIM  256
#define EPS_F    1e-8f

typedef __attribute__((ext_vector_type(8))) short bf16x8;
typedef __attribute__((ext_vector_type(4))) float f32x4;

__device__ __forceinline__ unsigned short f2bf(float f) {
    union { float f; unsigned u; } c; c.f = f;
    unsigned r = c.u + 0x7fffu + ((c.u >> 16) & 1u);   // RNE
    return (unsigned short)(r >> 16);
}
__device__ __forceinline__ float bf2f(unsigned short h) {
    union { float f; unsigned u; } c; c.u = ((unsigned)h) << 16;
    return c.f;
}

// async 16B/lane global->LDS (wave covers 64*16B = 1024B = one unpadded row)
__device__ __forceinline__ void gload_lds16(const void* g, void* l) {
    __builtin_amdgcn_global_load_lds(
        (const __attribute__((address_space(1))) unsigned int*)g,
        (__attribute__((address_space(3))) unsigned int*)l, 16, 0, 0);
}

// ---------------------------------------------------------------------------
// Round 5: maximize in-flight cold loads in k1. All global loads (stage A,
// stage B, wbf row, xv, colsum) are ISSUED before any convert/FMA consumes
// them, held in explicit registers (va[8]/vb[8] = 64 VGPR). launch_bounds
// (256,2) allows up to 256 VGPR while keeping 2 blocks/CU (waves halve only
// past 256). LDS layout, conversion arithmetic, MFMA order, colsum tree are
// byte-identical to round 4 -- only instruction ORDER changes.
// ---------------------------------------------------------------------------
#define LP1 264   // 528B rows (33x16B): rows step 4 banks -> 2-way = free
#define LP2 536   // 1072B rows (67x16B): rows step 12 banks -> 2-way = free

__global__ __launch_bounds__(256, 2) void k1_mod(
    const float* __restrict__ mods,    // [1024,256]
    const float* __restrict__ mod_w,   // [512,256]
    const float* __restrict__ mod_b,   // [512]
    const float* __restrict__ weight,  // [512,512]
    const float* __restrict__ x,       // [1024,512]
    unsigned short* __restrict__ t_bf, // [1024,512] bf16
    unsigned short* __restrict__ wbf)  // [512,512]  bf16
{
    __shared__ unsigned short Ah[32 * LP1], Al[32 * LP1];   // 33.8 KB
    __shared__ unsigned short Bh[32 * LP1], Bl[32 * LP1];   // 33.8 KB
    __shared__ float4 csm[32][8];                           // 4 KB
    __shared__ float colsum_s[32];

    const int tid = threadIdx.x;
    const int n0 = blockIdx.x * 32;     // 16 n-tiles
    const int m0 = blockIdx.y * 32;     // 32 m-tiles
    const int lane = tid & 63, wv = tid >> 6;              // 4 waves
    const int wm = (wv >> 1) * 16, wn = (wv & 1) * 16;     // 2x2 wave grid
    const int lr = lane & 15, lq = lane >> 4;

    // ======== ISSUE ALL GLOBAL LOADS FIRST (MLP), CONVERT LATER ========
    // same (r,c4) mapping as round 4: id=tid+i*256 -> r=(tid>>6)+4i, c4=tid&63
    const int rs = tid >> 6, c4s = tid & 63;

    float4 va[8], vb[8];
    #pragma unroll
    for (int i = 0; i < 8; i++)
        va[i] = *(const float4*)&mods[(m0 + rs + 4 * i) * MOD_DIM + c4s * 4];
    #pragma unroll
    for (int i = 0; i < 8; i++)
        vb[i] = *(const float4*)&mod_w[(n0 + rs + 4 * i) * MOD_DIM + c4s * 4];

    // wbf row (1 row/block, row = by*16+bx: bijection over [0,512))
    const int wrow = blockIdx.y * 16 + blockIdx.x;
    float4 wq = {0.f, 0.f, 0.f, 0.f};
    if (tid < 128) wq = *(const float4*)&weight[wrow * IN_DIMS + tid * 4];

    // epilogue x values
    float xv[4];
    {
        const int gn = n0 + wn + lr;
        #pragma unroll
        for (int rr = 0; rr < 4; rr++) {
            const int gm = m0 + wm + lq * 4 + rr;
            xv[rr] = x[gm * IN_DIMS + gn];
        }
    }

    // ---- colsum (same tree as round 4: row = rr + 32*it, rr in [0,32)) ----
    {
        const int c4 = tid & 7, rr = tid >> 3;
        float4 acc = {0.f, 0.f, 0.f, 0.f};
        #pragma unroll
        for (int it = 0; it < 16; it++) {
            const int row = rr + 32 * it;
            float4 v = *(const float4*)&weight[row * IN_DIMS + n0 + c4 * 4];
            acc.x += v.x * v.x; acc.y += v.y * v.y;
            acc.z += v.z * v.z; acc.w += v.w * v.w;
        }
        csm[rr][c4] = acc;
    }

    // ======== CONVERTS (all source data already in registers) ========
    #pragma unroll
    for (int i = 0; i < 8; i++) {
        const int r = rs + 4 * i;
        float4 v = va[i];
        ushort4 h, l;
        h.x = f2bf(v.x); l.x = f2bf(v.x - bf2f(h.x));
        h.y = f2bf(v.y); l.y = f2bf(v.y - bf2f(h.y));
        h.z = f2bf(v.z); l.z = f2bf(v.z - bf2f(h.z));
        h.w = f2bf(v.w); l.w = f2bf(v.w - bf2f(h.w));
        *(ushort4*)&Ah[r * LP1 + c4s * 4] = h;
        *(ushort4*)&Al[r * LP1 + c4s * 4] = l;
    }
    #pragma unroll
    for (int i = 0; i < 8; i++) {
        const int r = rs + 4 * i;
        float4 v = vb[i];
        ushort4 h, l;
        h.x = f2bf(v.x); l.x = f2bf(v.x - bf2f(h.x));
        h.y = f2bf(v.y); l.y = f2bf(v.y - bf2f(h.y));
        h.z = f2bf(v.z); l.z = f2bf(v.z - bf2f(h.z));
        h.w = f2bf(v.w); l.w = f2bf(v.w - bf2f(h.w));
        *(ushort4*)&Bh[r * LP1 + c4s * 4] = h;
        *(ushort4*)&Bl[r * LP1 + c4s * 4] = l;
    }
    if (tid < 128) {
        ushort4 h;
        h.x = f2bf(wq.x); h.y = f2bf(wq.y); h.z = f2bf(wq.z); h.w = f2bf(wq.w);
        *(ushort4*)&wbf[wrow * IN_DIMS + tid * 4] = h;
    }
    __syncthreads();

    // csm reduce (8 threads; overlaps other waves' MFMA)
    if (tid < 8) {
        float4 s = csm[0][tid];
        #pragma unroll
        for (int j = 1; j < 32; j++) {
            float4 v = csm[j][tid];
            s.x += v.x; s.y += v.y; s.z += v.z; s.w += v.w;
        }
        *(float4*)&colsum_s[tid * 4] = s;
    }

    // ---- MFMA: 8 kk-steps, 3 MFMA each (hh, hl, lh), 16x16 out/wave ----
    f32x4 acc = {};
    #pragma unroll
    for (int kk = 0; kk < 256; kk += 32) {
        const int ko = kk + lq * 8;
        bf16x8 ah = *(bf16x8*)&Ah[(wm + lr) * LP1 + ko];
        bf16x8 al = *(bf16x8*)&Al[(wm + lr) * LP1 + ko];
        bf16x8 bh = *(bf16x8*)&Bh[(wn + lr) * LP1 + ko];
        bf16x8 bl = *(bf16x8*)&Bl[(wn + lr) * LP1 + ko];
        acc = __builtin_amdgcn_mfma_f32_16x16x32_bf16(ah, bh, acc, 0, 0, 0);
        acc = __builtin_amdgcn_mfma_f32_16x16x32_bf16(ah, bl, acc, 0, 0, 0);
        acc = __builtin_amdgcn_mfma_f32_16x16x32_bf16(al, bh, acc, 0, 0, 0);
    }
    __syncthreads();   // colsum_s visibility for all waves

    // ---- epilogue: s -> t = x*s*rsqrt(s^2*colsum+eps) -> bf16 ----
    // C/D layout: col = lane&15, row = (lane>>4)*4 + reg
    {
        const int ln = wn + lr;
        const int gn = n0 + ln;
        const float cs = colsum_s[ln];
        const float mb = mod_b[gn];
        #pragma unroll
        for (int rr = 0; rr < 4; rr++) {
            const int gm = m0 + wm + lq * 4 + rr;
            const float s = acc[rr] + mb;
            const float tv = xv[rr] * s * rsqrtf(s * s * cs + EPS_F);
            t_bf[gm * IN_DIMS + gn] = f2bf(tv);
        }
    }
}

// ---------------------------------------------------------------------------
// K2: out = t_bf @ wbf^T + bias, both operands pre-converted bf16 (async
// global_load_lds staging only). 32x32 tile, 256 thr, 2 blocks/CU.
// (unchanged from round 4)
// ---------------------------------------------------------------------------
__global__ __launch_bounds__(256, 2) void k2_out(
    const unsigned short* __restrict__ t_bf, // [1024,512] bf16
    const unsigned short* __restrict__ wbf,  // [512,512]  bf16
    const float* __restrict__ bias,          // [512]
    float* __restrict__ out)                 // [1024,512]
{
    __shared__ unsigned short As[32 * LP2];   // 33.5 KB
    __shared__ unsigned short Bs[32 * LP2];   // 33.5 KB

    const int tid = threadIdx.x;
    const int n0 = blockIdx.x * 32;
    const int m0 = blockIdx.y * 32;
    const int lane = tid & 63, wv = tid >> 6;              // 4 waves
    const int wm = (wv >> 1) * 16, wn = (wv & 1) * 16;     // 2x2 wave grid
    const int lr = lane & 15, lq = lane >> 4;

    // bias prefetch (hide latency under staging)
    const float bv = bias[n0 + wn + lr];

    // ---- stage A (t_bf, 32x512 bf16): async, 8 rows/wave, 1 issue/row ----
    #pragma unroll
    for (int i = 0; i < 8; i++) {
        const int r = wv * 8 + i;
        gload_lds16(t_bf + (m0 + r) * IN_DIMS + lane * 8, &As[r * LP2]);
    }
    // ---- stage B (wbf, 32x512 bf16): async, 8 rows/wave ----
    #pragma unroll
    for (int i = 0; i < 8; i++) {
        const int r = wv * 8 + i;
        gload_lds16(wbf + (n0 + r) * IN_DIMS + lane * 8, &Bs[r * LP2]);
    }
    __syncthreads();   // drains vmcnt (incl. global_load_lds)

    f32x4 acc = {};
    #pragma unroll
    for (int kk = 0; kk < 512; kk += 32) {
        const int ko = kk + lq * 8;
        bf16x8 a = *(bf16x8*)&As[(wm + lr) * LP2 + ko];
        bf16x8 b = *(bf16x8*)&Bs[(wn + lr) * LP2 + ko];
        acc = __builtin_amdgcn_mfma_f32_16x16x32_bf16(a, b, acc, 0, 0, 0);
    }

    {
        const int gn = n0 + wn + lr;
        #pragma unroll
        for (int rr = 0; rr < 4; rr++) {
            const int gm = m0 + wm + lq * 4 + rr;
            out[gm * OUT_DIMS + gn] = acc[rr] + bv;
        }
    }
}

extern "C" void kernel_launch(void* const* d_in, const int* in_sizes, int n_in,
                              void* d_out, int out_size, void* d_ws, size_t ws_size,
                              hipStream_t stream)
{
    const float* modulations = (const float*)d_in[0]; // [1024, 256]
    const float* x           = (const float*)d_in[1]; // [1024, 512]
    const float* weight      = (const float*)d_in[2]; // [512, 512]
    const float* bias        = (const float*)d_in[3]; // [512]
    const float* mod_w       = (const float*)d_in[4]; // [512, 256]
    const float* mod_b       = (const float*)d_in[5]; // [512]
    float* out = (float*)d_out;                       // [1024, 512]

    unsigned short* t_bf = (unsigned short*)d_ws;                  // 1 MB
    unsigned short* wbf  = (unsigned short*)d_ws + (1024 * 512);   // 512 KB

    k1_mod<<<dim3(16, 32), 256, 0, stream>>>(
        modulations, mod_w, mod_b, weight, x, t_bf, wbf);

    k2_out<<<dim3(16, 32), 256, 0, stream>>>(
        t_bf, wbf, bias, out);
}